// Round 3
// baseline (2024.765 us; speedup 1.0000x reference)
//
#include <hip/hip_runtime.h>
#include <math.h>

// Problem constants
#define HD    1024      // hidden size
#define SEQL  512       // sequence length
#define NLAB  122       // labels
#define NWG   256       // workgroups in persistent recurrent kernel (1 per CU)
#define JPW   4         // h-columns (j) per workgroup  (NWG*JPW == HD)

// Workspace layout (bytes). Total ≈ 27.3 MB.
#define OFF_MSG   ((size_t)0)          // h msg: 2*1024 u64 (tag<<32|h_bits)    = 16384 B
#define OFF_HALL  ((size_t)16384)      // h_all: 512*1024 fp32                  = 2097152 B
#define OFF_GATES ((size_t)2113536)    // gates_x: 512*4096 fp32 (swizzled)     = 8388608 B
#define OFF_WR    ((size_t)10502144)   // W_r2: 4096*1024 fp32 (swizzled)       = 16777216 B
// end = 27279360

// ---------------------------------------------------------------------------
// Prep: W_r2 swizzled so thread `t` of WG `g` reads its 64-float slice as 16
// contiguous float4s:  W_r2[((g*256 + t)*16 + i4)*4 + c]
//   t: row = t&15 (gate = row>>2, jj = row&3), kq = t>>4
//   element (i4,c): k = kq*64 + i4*4 + c,  R = gate*1024 + g*4 + jj
//   value = W_ih[R][4096+k] + W_hh[R][k]
__global__ __launch_bounds__(256) void prep_wr(const float* __restrict__ W_ih,
                                               const float* __restrict__ W_hh,
                                               float* __restrict__ W_r2) {
    int idx4 = blockIdx.x * 256 + threadIdx.x;   // float4 index, < 1048576
    int g  = idx4 >> 12;
    int t  = (idx4 >> 4) & 255;
    int i4 = idx4 & 15;
    int row = t & 15;
    int gate = row >> 2;
    int jj   = row & 3;
    int kq   = t >> 4;
    int k = kq * 64 + i4 * 4;
    int R = (gate << 10) + (g << 2) + jj;
    float4 wa = *(const float4*)(W_ih + (size_t)R * 5120 + 4096 + k);
    float4 wb = *(const float4*)(W_hh + (size_t)R * 1024 + k);
    float4 o;
    o.x = wa.x + wb.x; o.y = wa.y + wb.y; o.z = wa.z + wb.z; o.w = wa.w + wb.w;
    *(float4*)(W_r2 + (size_t)idx4 * 4) = o;
}

// ---------------------------------------------------------------------------
// gates_x[t][g*16 + gate*4 + jj] = b[r] + sum_k feats[t][k] * W_ih[r][k]
//   (r = gate*1024 + g*4 + jj — store swizzled so WG g's 16 values are one
//    contiguous 64 B line per step)
// feats[t] = concat(x[t] (2048), hi[t] (2048)). 64x64 tile, BK=16, fp32 VALU.
__global__ __launch_bounds__(256) void gates_gemm(const float* __restrict__ x,
                                                  const float* __restrict__ hi,
                                                  const float* __restrict__ W_ih,
                                                  const float* __restrict__ b_ih,
                                                  const float* __restrict__ b_hh,
                                                  float* __restrict__ gates_x) {
    __shared__ float As[16][68];
    __shared__ float Bs[16][68];
    const int tid = threadIdx.x;
    const int r0 = blockIdx.x * 64;
    const int t0 = blockIdx.y * 64;
    const int tx = tid & 15, ty = tid >> 4;
    const int l   = tid & 63;
    const int kq4 = tid >> 6;

    float acc[4][4] = {};
    for (int kb = 0; kb < 4096; kb += 16) {
        int k = kb + kq4 * 4;
        const float* asrc = (k < 2048) ? (x  + (size_t)(t0 + l) * 2048 + k)
                                       : (hi + (size_t)(t0 + l) * 2048 + (k - 2048));
        float4 a4 = *(const float4*)asrc;
        float4 b4 = *(const float4*)(W_ih + (size_t)(r0 + l) * 5120 + k);
        __syncthreads();
        As[kq4 * 4 + 0][l] = a4.x; As[kq4 * 4 + 1][l] = a4.y;
        As[kq4 * 4 + 2][l] = a4.z; As[kq4 * 4 + 3][l] = a4.w;
        Bs[kq4 * 4 + 0][l] = b4.x; Bs[kq4 * 4 + 1][l] = b4.y;
        Bs[kq4 * 4 + 2][l] = b4.z; Bs[kq4 * 4 + 3][l] = b4.w;
        __syncthreads();
        #pragma unroll
        for (int kk = 0; kk < 16; ++kk) {
            float4 av = *(const float4*)&As[kk][ty * 4];
            float4 bv = *(const float4*)&Bs[kk][tx * 4];
            float a_[4] = {av.x, av.y, av.z, av.w};
            float b_[4] = {bv.x, bv.y, bv.z, bv.w};
            #pragma unroll
            for (int i = 0; i < 4; ++i)
                #pragma unroll
                for (int j = 0; j < 4; ++j)
                    acc[i][j] += a_[i] * b_[j];
        }
    }
    int r = r0 + tx * 4;
    float bias[4];
    #pragma unroll
    for (int j = 0; j < 4; ++j) bias[j] = b_ih[r + j] + b_hh[r + j];
    // swizzled store: r..r+3 share gate and g, jj = 0..3 contiguous
    int gate = r >> 10;
    int gw   = (r & 1023) >> 2;
    #pragma unroll
    for (int i = 0; i < 4; ++i) {
        float4 o;
        o.x = acc[i][0] + bias[0]; o.y = acc[i][1] + bias[1];
        o.z = acc[i][2] + bias[2]; o.w = acc[i][3] + bias[3];
        *(float4*)(gates_x + (size_t)(t0 + ty * 4 + i) * 4096 + gw * 16 + gate * 4) = o;
    }
}

// ---------------------------------------------------------------------------
// Persistent recurrent kernel. 256 WGs x 256 threads, one per CU.
// WG g owns j in [g*4, g*4+4): 16 gate rows. Thread: row = tid&15 (gate,jj),
// k-slice kq*64..+64 (kq = tid>>4). Weights pinned in VGPRs via asm barrier
// (16 float4 = 64 VGPRs/thread) — R1's compiler sank them to per-step L2
// streaming (VGPR_Count=88 proved it), which was ~2300 cyc/step.
// h exchange: single-hop tag-in-word protocol (tag s+1 <<32 | f32 h bits),
// RELAXED agent atomics only -> no buffer_inv cache wipes.
__global__ __launch_bounds__(256, 1) void lstm_rec(const float* __restrict__ gates_x,
                                                   const float* __restrict__ W_r2,
                                                   float* __restrict__ h_all,
                                                   unsigned long long* h_msg) {
    const int g   = blockIdx.x;
    const int tid = threadIdx.x;
    const int row = tid & 15;    // local gate-row: gate = row>>2, jj = row&3
    const int kq  = tid >> 4;    // k-slice [kq*64, kq*64+64)
    __shared__ float4 h_s[256];          // h_{s-1}, float4 i covers k = i*4..+3
    __shared__ float  partial[16][17];
    __shared__ float  gv_s[16];

    // one-time weight load -> registers, pinned opaque so they can't be sunk
    float4 w4[16];
    {
        const float4* Wp = ((const float4*)W_r2) + ((size_t)(g * 256 + tid) * 16);
        #pragma unroll
        for (int i = 0; i < 16; ++i) w4[i] = Wp[i];
        #pragma unroll
        for (int i = 0; i < 16; ++i)
            asm volatile("" : "+v"(w4[i].x), "+v"(w4[i].y), "+v"(w4[i].z), "+v"(w4[i].w));
    }

    float c = 0.f;               // cell state, meaningful in tid<4 lanes
    int budget = 4000000;        // anti-hang poll budget

    for (int s = 0; s < SEQL; ++s) {
        // independent prefetch: this WG's 16 gate values (one 64 B line)
        float gx = 0.f;
        if (tid < 16)
            gx = gates_x[(size_t)s * 4096 + g * 16 + tid];

        // poll h_{s-1}: thread tid owns msg words tid*4 .. tid*4+3
        {
            const unsigned long long* buf = h_msg + (size_t)(s & 1) * HD + tid * 4;
            const unsigned want = (unsigned)s;
            unsigned long long v0, v1, v2, v3;
            for (;;) {
                v0 = __hip_atomic_load(buf + 0, __ATOMIC_RELAXED, __HIP_MEMORY_SCOPE_AGENT);
                v1 = __hip_atomic_load(buf + 1, __ATOMIC_RELAXED, __HIP_MEMORY_SCOPE_AGENT);
                v2 = __hip_atomic_load(buf + 2, __ATOMIC_RELAXED, __HIP_MEMORY_SCOPE_AGENT);
                v3 = __hip_atomic_load(buf + 3, __ATOMIC_RELAXED, __HIP_MEMORY_SCOPE_AGENT);
                if ((unsigned)(v0 >> 32) == want && (unsigned)(v1 >> 32) == want &&
                    (unsigned)(v2 >> 32) == want && (unsigned)(v3 >> 32) == want) break;
                if (--budget < 0) break;
            }
            float4 hv;
            hv.x = __uint_as_float((unsigned)v0);
            hv.y = __uint_as_float((unsigned)v1);
            hv.z = __uint_as_float((unsigned)v2);
            hv.w = __uint_as_float((unsigned)v3);
            h_s[tid] = hv;
        }
        __syncthreads();

        // matvec slice: 1 row x 64 k per thread, weights from registers
        float a0 = 0.f, a1 = 0.f, a2 = 0.f, a3 = 0.f;
        #pragma unroll
        for (int i = 0; i < 16; ++i) {
            float4 h4 = h_s[kq * 16 + i];
            a0 += w4[i].x * h4.x;
            a1 += w4[i].y * h4.y;
            a2 += w4[i].z * h4.z;
            a3 += w4[i].w * h4.w;
        }
        partial[row][kq] = (a0 + a1) + (a2 + a3);
        __syncthreads();

        if (tid < 16) {
            float sum = gx;
            #pragma unroll
            for (int q = 0; q < 16; ++q) sum += partial[tid][q];
            gv_s[tid] = sum;
        }
        __syncthreads();

        if (tid < JPW) {
            float gi = gv_s[tid], gf = gv_s[4 + tid], gc = gv_s[8 + tid], go = gv_s[12 + tid];
            float si = 1.f / (1.f + __expf(-gi));
            float sf = 1.f / (1.f + __expf(-gf));
            float so = 1.f / (1.f + __expf(-go));
            float tg = 2.f / (1.f + __expf(-2.f * gc)) - 1.f;   // tanh(gc)
            c = sf * c + si * tg;
            float th = 2.f / (1.f + __expf(-2.f * c)) - 1.f;    // tanh(c)
            float h = so * th;
            int j = g * JPW + tid;
            h_all[(size_t)s * HD + j] = h;   // consumed by fc_out after kernel end
            unsigned long long m = ((unsigned long long)(unsigned)(s + 1) << 32)
                                 | (unsigned long long)__float_as_uint(h);
            __hip_atomic_store(h_msg + (size_t)((s + 1) & 1) * HD + j, m,
                               __ATOMIC_RELAXED, __HIP_MEMORY_SCOPE_AGENT);
        }
        // no trailing barrier needed: gv_s is next written only after the
        // first two __syncthreads of iteration s+1
    }
}

// ---------------------------------------------------------------------------
// out[t][lab] = b_fc[lab] + sum_k h_all[t][k] * W_fc[lab][k]
__global__ __launch_bounds__(128) void fc_out(const float* __restrict__ h_all,
                                              const float* __restrict__ W_fc,
                                              const float* __restrict__ b_fc,
                                              float* __restrict__ out) {
    const int t = blockIdx.x;
    const int tid = threadIdx.x;
    __shared__ float4 h_s[256];
    const float4* hsrc = (const float4*)(h_all + (size_t)t * HD);
    h_s[tid] = hsrc[tid];
    h_s[tid + 128] = hsrc[tid + 128];
    __syncthreads();
    if (tid < NLAB) {
        float acc = b_fc[tid];
        const float4* wp = (const float4*)(W_fc + (size_t)tid * HD);
        #pragma unroll 8
        for (int k4 = 0; k4 < 256; ++k4) {
            float4 w = wp[k4];
            float4 h = h_s[k4];
            acc += w.x*h.x + w.y*h.y + w.z*h.z + w.w*h.w;
        }
        out[(size_t)t * NLAB + tid] = acc;
    }
}

// ---------------------------------------------------------------------------
extern "C" void kernel_launch(void* const* d_in, const int* in_sizes, int n_in,
                              void* d_out, int out_size, void* d_ws, size_t ws_size,
                              hipStream_t stream) {
    const float* x    = (const float*)d_in[0];
    const float* hi   = (const float*)d_in[1];
    const float* W_ih = (const float*)d_in[2];
    const float* W_hh = (const float*)d_in[3];
    const float* b_ih = (const float*)d_in[4];
    const float* b_hh = (const float*)d_in[5];
    const float* W_fc = (const float*)d_in[6];
    const float* b_fc = (const float*)d_in[7];
    float* out = (float*)d_out;

    char* ws = (char*)d_ws;
    unsigned long long* h_msg = (unsigned long long*)(ws + OFF_MSG);
    float* h_all   = (float*)(ws + OFF_HALL);
    float* gates_x = (float*)(ws + OFF_GATES);
    float* W_r2    = (float*)(ws + OFF_WR);

    // zero the msg buffer: h_{-1}=0 with tag 0 (ws is re-poisoned 0xAA each call)
    hipMemsetAsync(d_ws, 0, 16384, stream);

    prep_wr<<<4096, 256, 0, stream>>>(W_ih, W_hh, W_r2);

    dim3 gg(64, 8);
    gates_gemm<<<gg, 256, 0, stream>>>(x, hi, W_ih, b_ih, b_hh, gates_x);

    lstm_rec<<<NWG, 256, 0, stream>>>(gates_x, W_r2, h_all, h_msg);

    fc_out<<<SEQL, 128, 0, stream>>>(h_all, W_fc, b_fc, out);
}